// Round 7
// baseline (373.985 us; speedup 1.0000x reference)
//
#include <hip/hip_runtime.h>
#include <hip/hip_bf16.h>
#include <math.h>

#define N_NODES 50000
#define N_EDGES 1600000
#define N_FEAT  256
#define HIDDEN  32
#define N_CLASS 64
#define NBUCK   391      // ceil(50000/128) buckets of 128 dst nodes
#define EPB     7168     // edges per bin_edges block (224 blocks)
#define SCAP    5120     // fixed bucket capacity (mean 4093, sigma 64 -> +16 sigma)
#define CAP     4608     // LDS stage cap in build_csr

typedef _Float16 half_t;
typedef _Float16 half8 __attribute__((ext_vector_type(8)));

// ---------------- stage 1: bin edges directly into fixed-capacity buckets ----
// st entry: x = (dloc<<16) | src  (dloc = dst&127), y = val bits.

__global__ __launch_bounds__(256) void bin_edges(const int* __restrict__ src,
                                                 const int* __restrict__ dst,
                                                 const float* __restrict__ val,
                                                 int* __restrict__ bcur,
                                                 int2* __restrict__ st) {
  __shared__ int h[NBUCK];
  __shared__ int lcur[NBUCK];
  __shared__ int gbase[NBUCK];
  int t = threadIdx.x;
  for (int i = t; i < NBUCK; i += 256) { h[i] = 0; lcur[i] = 0; }
  __syncthreads();
  int base = blockIdx.x * EPB;
  int nloc = min(EPB, N_EDGES - base);
  for (int i = t; i < nloc; i += 256) atomicAdd(&h[dst[base + i] >> 7], 1);
  __syncthreads();
  // one global atomic per touched bucket reserves a contiguous window
  for (int i = t; i < NBUCK; i += 256) {
    int c = h[i];
    gbase[i] = c ? atomicAdd(&bcur[i], c) : 0;
  }
  __syncthreads();
  for (int i = t; i < nloc; i += 256) {
    int e = base + i;
    int d = dst[e];
    int b = d >> 7;
    int pos = gbase[b] + atomicAdd(&lcur[b], 1);
    if (pos < SCAP)
      st[b * SCAP + pos] = make_int2(((d & 127) << 16) | src[e],
                                     __float_as_int(val[e]));
  }
}

// ---------------- stage 2: per-bucket node-grouping -> rr(beg,end) + ep ------

__global__ __launch_bounds__(256) void build_csr(const int* __restrict__ bcur,
                                                 const int2* __restrict__ st,
                                                 int2* __restrict__ rr,
                                                 int2* __restrict__ ep) {
  __shared__ int2 stage[CAP];   // 36.9 KB
  __shared__ int lh[128], lstart[128], lcur[128];
  int b = blockIdx.x, t = threadIdx.x;
  int n = min(min(bcur[b], SCAP), CAP);
  int gb = b * SCAP;
  for (int i = t; i < 128; i += 256) { lh[i] = 0; lcur[i] = 0; }
  __syncthreads();
  for (int i = t; i < n; i += 256) {
    int2 v = st[gb + i];
    stage[i] = v;
    atomicAdd(&lh[(v.x >> 16) & 127], 1);
  }
  __syncthreads();
  if (t < 64) {
    int a0 = lh[2 * t], a1 = lh[2 * t + 1];
    int s0 = a0 + a1;
    int run = s0;
#pragma unroll
    for (int off = 1; off < 64; off <<= 1) {
      int u = __shfl_up(run, off);
      if (t >= off) run += u;
    }
    int excl = run - s0;
    lstart[2 * t] = excl;
    lstart[2 * t + 1] = excl + a0;
  }
  __syncthreads();
  int nodebase = b * 128;
  int nn = min(128, N_NODES - nodebase);
  for (int i = t; i < nn; i += 256)
    rr[nodebase + i] = make_int2(gb + lstart[i], gb + lstart[i] + lh[i]);
  for (int i = t; i < n; i += 256) {
    int2 v = stage[i];
    int d = (v.x >> 16) & 127;
    int pos = lstart[d] + atomicAdd(&lcur[d], 1);
    ep[gb + pos] = make_int2(v.x & 0xffff, v.y);
  }
}

// ---------------- MLP + softmax -> p0 (single-phase, thread = node) ----------
// 128 thr/block = 128 nodes; h[32] and p[64] fully in registers; x staged per
// 32-feat chunk in swizzle-free LDS (stride 133 -> 2-way max); W via s_loads.

__global__ __launch_bounds__(128) void mlp_kernel(const float* __restrict__ x,
                                                  const float* __restrict__ W1,
                                                  const float* __restrict__ b1,
                                                  const float* __restrict__ W2,
                                                  const float* __restrict__ b2,
                                                  half_t* __restrict__ P) {
  __shared__ float xs[32 * 133];        // 17.0 KB
  __shared__ half_t ps[128 * 72];       // 18.0 KB (144B rows, 16B aligned)
  int t = threadIdx.x;
  int n0 = blockIdx.x * 128;

  float h[HIDDEN];
#pragma unroll
  for (int j = 0; j < HIDDEN; ++j) h[j] = 0.f;

  for (int kc = 0; kc < 8; ++kc) {
    // stage x[n0..n0+127][kc*32..+32): coalesced float4 reads
#pragma unroll
    for (int pass = 0; pass < 8; ++pass) {
      int idx = pass * 128 + t;     // 0..1023 float4 slots
      int n = idx >> 3;             // node-local 0..127
      int c4 = idx & 7;
      float4 v = make_float4(0.f, 0.f, 0.f, 0.f);
      if (n0 + n < N_NODES)
        v = *(const float4*)(x + (size_t)(n0 + n) * N_FEAT + kc * 32 + c4 * 4);
      xs[(c4 * 4 + 0) * 133 + n] = v.x;
      xs[(c4 * 4 + 1) * 133 + n] = v.y;
      xs[(c4 * 4 + 2) * 133 + n] = v.z;
      xs[(c4 * 4 + 3) * 133 + n] = v.w;
    }
    __syncthreads();
#pragma unroll 4
    for (int k = 0; k < 32; ++k) {
      float xk = xs[k * 133 + t];
      const float* wr = W1 + (kc * 32 + k) * HIDDEN;   // uniform -> s_load
#pragma unroll
      for (int j = 0; j < HIDDEN; ++j) h[j] = fmaf(xk, wr[j], h[j]);
    }
    __syncthreads();
  }

  // bias + ReLU, then layer 2 entirely in registers
  float p[N_CLASS];
#pragma unroll
  for (int c = 0; c < N_CLASS; ++c) p[c] = b2[c];
#pragma unroll 4
  for (int k = 0; k < HIDDEN; ++k) {
    float hk = fmaxf(h[k] + b1[k], 0.f);
    const float* w2r = W2 + k * N_CLASS;               // uniform -> s_load
#pragma unroll
    for (int c = 0; c < N_CLASS; ++c) p[c] = fmaf(hk, w2r[c], p[c]);
  }

  // per-thread softmax over 64 register values
  float m = p[0];
#pragma unroll
  for (int c = 1; c < N_CLASS; ++c) m = fmaxf(m, p[c]);
  float s = 0.f;
#pragma unroll
  for (int c = 0; c < N_CLASS; ++c) { p[c] = expf(p[c] - m); s += p[c]; }
  float inv = 1.f / s;

  // fp16 rows to LDS, then coalesced global store
#pragma unroll
  for (int c0 = 0; c0 < N_CLASS; c0 += 8) {
    half8 o;
#pragma unroll
    for (int i = 0; i < 8; ++i) o[i] = (half_t)(p[c0 + i] * inv);
    *(half8*)(ps + t * 72 + c0) = o;
  }
  __syncthreads();
#pragma unroll
  for (int pass = 0; pass < 8; ++pass) {
    int idx = pass * 128 + t;     // 0..1023 half8 slots
    int n = idx >> 3;
    int c0 = (idx & 7) * 8;
    if (n0 + n < N_NODES)
      *(half8*)(P + (size_t)(n0 + n) * N_CLASS + c0) =
          *(const half8*)(ps + n * 72 + c0);
  }
}

// ---------------- SpMM + 0.5*tanh (+ fused final softmax) ----------------
// wave per dst node; 8 edge-subgroups x 8 channel-octets; 16B half8 gathers.

template <int FINAL>
__global__ __launch_bounds__(256) void spmm_kernel(const int2* __restrict__ rr,
                                                   const int2* __restrict__ ep,
                                                   const half_t* __restrict__ pin,
                                                   void* __restrict__ pout_) {
  int node = blockIdx.x * 4 + (threadIdx.x >> 6);
  int lane = threadIdx.x & 63;
  int g = lane >> 3;     // edge subgroup 0..7
  int s = lane & 7;      // channel octet: channels 8s..8s+7
  int2 be = rr[node];
  int beg = be.x, end = be.y;
  float acc[8];
#pragma unroll
  for (int i = 0; i < 8; ++i) acc[i] = 0.f;
  const long long* epl = (const long long*)ep;
  for (int base = beg; base < end; base += 64) {
    int idx = base + lane;
    long long raw = (idx < end) ? __builtin_nontemporal_load(epl + idx) : 0LL;
    int ex = (int)raw;
    float ev = __int_as_float((int)(raw >> 32));
    int cnt = min(64, end - base);
#pragma unroll 4
    for (int j = g; j < cnt; j += 8) {
      int   sj = __shfl(ex, j);
      float vj = __shfl(ev, j);
      half8 hv = *(const half8*)(pin + ((size_t)sj << 6) + (s << 3));
#pragma unroll
      for (int i = 0; i < 8; ++i) acc[i] = fmaf(vj, (float)hv[i], acc[i]);
    }
  }
  // reduce across the 8 edge subgroups (lane bits 3,4,5)
#pragma unroll
  for (int off = 8; off <= 32; off <<= 1)
#pragma unroll
    for (int i = 0; i < 8; ++i) acc[i] += __shfl_xor(acc[i], off);
  float r[8];
#pragma unroll
  for (int i = 0; i < 8; ++i) r[i] = 0.5f * tanhf(acc[i]);
  if (FINAL) {
    float m = r[0];
#pragma unroll
    for (int i = 1; i < 8; ++i) m = fmaxf(m, r[i]);
    m = fmaxf(m, __shfl_xor(m, 1));
    m = fmaxf(m, __shfl_xor(m, 2));
    m = fmaxf(m, __shfl_xor(m, 4));
    float e[8], sum = 0.f;
#pragma unroll
    for (int i = 0; i < 8; ++i) { e[i] = expf(r[i] - m); sum += e[i]; }
    sum += __shfl_xor(sum, 1);
    sum += __shfl_xor(sum, 2);
    sum += __shfl_xor(sum, 4);
    float inv = 1.f / sum;
    if (g == 0) {
      float* op = (float*)pout_ + ((size_t)node << 6) + (s << 3);
      *(float4*)op = make_float4(e[0] * inv, e[1] * inv, e[2] * inv, e[3] * inv);
      *(float4*)(op + 4) = make_float4(e[4] * inv, e[5] * inv, e[6] * inv, e[7] * inv);
    }
  } else {
    if (g == 0) {
      half8 o;
#pragma unroll
      for (int i = 0; i < 8; ++i) o[i] = (half_t)r[i];
      *(half8*)((half_t*)pout_ + ((size_t)node << 6) + (s << 3)) = o;
    }
  }
}

// ---------------- launch ----------------

extern "C" void kernel_launch(void* const* d_in, const int* in_sizes, int n_in,
                              void* d_out, int out_size, void* d_ws, size_t ws_size,
                              hipStream_t stream) {
  const float* x    = (const float*)d_in[0];
  const int*   esrc = (const int*)d_in[1];
  const int*   edst = (const int*)d_in[2];
  const float* evl  = (const float*)d_in[3];
  const float* W1   = (const float*)d_in[4];
  const float* b1   = (const float*)d_in[5];
  const float* W2   = (const float*)d_in[6];
  const float* b2   = (const float*)d_in[7];

  char* ws = (char*)d_ws;
  int2*   st   = (int2*)  (ws);               // 16.0 MB (dead after build_csr)
  half_t* Pa   = (half_t*)(ws);               // 6.4 MB (aliases st)
  half_t* Pb   = (half_t*)(ws + 6400000);     // 6.4 MB (aliases st)
  int2*   ep   = (int2*)  (ws + 16015360);    // 16.0 MB
  int*    bcur = (int*)   (ws + 32030720);    // 391 ints
  int2*   rr   = (int2*)  (ws + 32032384);    // 50000 int2

  hipMemsetAsync(bcur, 0, NBUCK * sizeof(int), stream);

  bin_edges<<<224, 256, 0, stream>>>(esrc, edst, evl, bcur, st);
  build_csr<<<NBUCK, 256, 0, stream>>>(bcur, st, rr, ep);

  mlp_kernel<<<NBUCK, 128, 0, stream>>>(x, W1, b1, W2, b2, Pa);

  spmm_kernel<0><<<12500, 256, 0, stream>>>(rr, ep, Pa, Pb);
  spmm_kernel<0><<<12500, 256, 0, stream>>>(rr, ep, Pb, Pa);
  spmm_kernel<0><<<12500, 256, 0, stream>>>(rr, ep, Pa, Pb);
  spmm_kernel<1><<<12500, 256, 0, stream>>>(rr, ep, Pb, d_out);
}

// Round 8
// 316.059 us; speedup vs baseline: 1.1833x; 1.1833x over previous
//
#include <hip/hip_runtime.h>
#include <hip/hip_bf16.h>
#include <math.h>

#define N_NODES 50000
#define N_EDGES 1600000
#define N_FEAT  256
#define HIDDEN  32
#define N_CLASS 64
#define NBUCK   391      // ceil(50000/128) buckets of 128 dst nodes
#define EPB     7168     // edges per bin_edges block (224 blocks)
#define SCAP    5120     // fixed bucket capacity (mean 4093, sigma 64)
#define CAP     4608     // LDS stage cap in build_csr

typedef _Float16 half_t;
typedef _Float16 half8 __attribute__((ext_vector_type(8)));

// ---------------- stage 1: bin edges into fixed-capacity bucket windows ------
// LDS-staged, bucket-grouped flush -> coalesced global writes.
// st entry: x = (dst<<16) | src, y = val bits.

__global__ __launch_bounds__(256) void bin_edges(const int* __restrict__ src,
                                                 const int* __restrict__ dst,
                                                 const float* __restrict__ val,
                                                 int* __restrict__ bcur,
                                                 int2* __restrict__ st) {
  __shared__ int h[NBUCK];
  __shared__ int lstart[NBUCK];
  __shared__ int lcur[NBUCK];
  __shared__ int gbase[NBUCK];
  __shared__ int2 stage[EPB];   // 56 KB
  int t = threadIdx.x;
  for (int i = t; i < NBUCK; i += 256) { h[i] = 0; lcur[i] = 0; }
  __syncthreads();
  int base = blockIdx.x * EPB;
  int nloc = min(EPB, N_EDGES - base);
  for (int i = t; i < nloc; i += 256) atomicAdd(&h[dst[base + i] >> 7], 1);
  __syncthreads();
  // exclusive scan of h[391]: wave 0, 7 buckets per lane
  if (t < 64) {
    int loc[7];
    int s0 = 0;
#pragma unroll
    for (int i = 0; i < 7; ++i) {
      int b = t * 7 + i;
      int c = (b < NBUCK) ? h[b] : 0;
      loc[i] = s0; s0 += c;
    }
    int run = s0;
#pragma unroll
    for (int off = 1; off < 64; off <<= 1) {
      int u = __shfl_up(run, off);
      if (t >= off) run += u;
    }
    int excl = run - s0;
#pragma unroll
    for (int i = 0; i < 7; ++i) {
      int b = t * 7 + i;
      if (b < NBUCK) lstart[b] = excl + loc[i];
    }
  }
  __syncthreads();
  // reserve window space: one global atomic per touched bucket per block
  for (int i = t; i < NBUCK; i += 256) {
    int c = h[i];
    gbase[i] = c ? atomicAdd(&bcur[i], c) : 0;
  }
  __syncthreads();
  // place edges into LDS staging grouped by bucket
  for (int i = t; i < nloc; i += 256) {
    int e = base + i;
    int d = dst[e];
    int b = d >> 7;
    int pos = lstart[b] + atomicAdd(&lcur[b], 1);
    stage[pos] = make_int2((d << 16) | src[e], __float_as_int(val[e]));
  }
  __syncthreads();
  // flush: consecutive slots within a bucket -> consecutive global addrs
  for (int i = t; i < nloc; i += 256) {
    int2 v = stage[i];
    int b = (int)(((unsigned)v.x) >> 23);          // dst>>7
    int pos = gbase[b] + (i - lstart[b]);
    if (pos < SCAP) st[(size_t)b * SCAP + pos] = v;
  }
}

// ---------------- stage 2: per-bucket node-grouping -> rr(beg,end) + ep ------

__global__ __launch_bounds__(256) void build_csr(const int* __restrict__ bcur,
                                                 const int2* __restrict__ st,
                                                 int2* __restrict__ rr,
                                                 int2* __restrict__ ep) {
  __shared__ int2 stage[CAP];   // 36.9 KB
  __shared__ int lh[128], lstart[128], lcur[128];
  int b = blockIdx.x, t = threadIdx.x;
  int n = min(min(bcur[b], SCAP), CAP);
  int gb = b * SCAP;
  for (int i = t; i < 128; i += 256) { lh[i] = 0; lcur[i] = 0; }
  __syncthreads();
  for (int i = t; i < n; i += 256) {
    int2 v = st[gb + i];
    stage[i] = v;
    atomicAdd(&lh[(v.x >> 16) & 127], 1);
  }
  __syncthreads();
  if (t < 64) {
    int a0 = lh[2 * t], a1 = lh[2 * t + 1];
    int s0 = a0 + a1;
    int run = s0;
#pragma unroll
    for (int off = 1; off < 64; off <<= 1) {
      int u = __shfl_up(run, off);
      if (t >= off) run += u;
    }
    int excl = run - s0;
    lstart[2 * t] = excl;
    lstart[2 * t + 1] = excl + a0;
  }
  __syncthreads();
  int nodebase = b * 128;
  int nn = min(128, N_NODES - nodebase);
  for (int i = t; i < nn; i += 256)
    rr[nodebase + i] = make_int2(gb + lstart[i], gb + lstart[i] + lh[i]);
  for (int i = t; i < n; i += 256) {
    int2 v = stage[i];
    int d = (v.x >> 16) & 127;
    int pos = lstart[d] + atomicAdd(&lcur[d], 1);
    ep[gb + pos] = make_int2(v.x & 0xffff, v.y);
  }
}

// ---------------- MLP + softmax -> p0 (j-split, no reduction) ----------------
// 512 thr / 64 nodes; wave w owns L1 j-slice [4w,4w+4) and L2 classes
// [8w,8w+8) -> no cross-wave partial sums. x tiled per 64-feat chunk in LDS
// with rotate swizzle col=(row+4*c4)&63 (2-way on write AND read = free).

__global__ __launch_bounds__(512) void mlp_kernel(const float* __restrict__ x,
                                                  const float* __restrict__ W1,
                                                  const float* __restrict__ b1,
                                                  const float* __restrict__ W2,
                                                  const float* __restrict__ b2,
                                                  half_t* __restrict__ P) {
  __shared__ float lds[4416 + 2112];   // xs[4096]/ps[64*65] union + hfull[64*33]
  float* xs = lds;
  float* ps = lds;
  float* hfull = lds + 4416;

  int t = threadIdx.x;
  int w = __builtin_amdgcn_readfirstlane(t >> 6);   // 0..7
  int l = t & 63;
  int n0 = blockIdx.x * 64;

  int row0 = t >> 4,          c40 = t & 15;          // slot pass 0
  int row1 = (512 + t) >> 4,  c41 = t & 15;          // slot pass 1 (row+32)
  bool ok0 = (n0 + row0) < N_NODES;
  bool ok1 = (n0 + row1) < N_NODES;

  float4 v0 = make_float4(0.f, 0.f, 0.f, 0.f), v1 = v0;
  if (ok0) v0 = *(const float4*)(x + (size_t)(n0 + row0) * N_FEAT + c40 * 4);
  if (ok1) v1 = *(const float4*)(x + (size_t)(n0 + row1) * N_FEAT + c41 * 4);

  float h[4] = {0.f, 0.f, 0.f, 0.f};
  for (int kc = 0; kc < 4; ++kc) {
    {
      int f0 = c40 * 4, col = (row0 + f0) & 63;      // 4*c4 rotate
      xs[(f0 + 0) * 64 + col] = v0.x;
      xs[(f0 + 1) * 64 + col] = v0.y;
      xs[(f0 + 2) * 64 + col] = v0.z;
      xs[(f0 + 3) * 64 + col] = v0.w;
      int f1 = c41 * 4, col1 = (row1 + f1) & 63;
      xs[(f1 + 0) * 64 + col1] = v1.x;
      xs[(f1 + 1) * 64 + col1] = v1.y;
      xs[(f1 + 2) * 64 + col1] = v1.z;
      xs[(f1 + 3) * 64 + col1] = v1.w;
    }
    __syncthreads();
    if (kc < 3) {   // register prefetch of next chunk (overlaps compute)
      v0 = make_float4(0.f, 0.f, 0.f, 0.f); v1 = v0;
      if (ok0) v0 = *(const float4*)(x + (size_t)(n0 + row0) * N_FEAT + (kc + 1) * 64 + c40 * 4);
      if (ok1) v1 = *(const float4*)(x + (size_t)(n0 + row1) * N_FEAT + (kc + 1) * 64 + c41 * 4);
    }
#pragma unroll 8
    for (int k = 0; k < 64; ++k) {
      float xk = xs[k * 64 + ((l + (k & 60)) & 63)];
      const float* wr = W1 + (size_t)(kc * 64 + k) * HIDDEN + 4 * w;  // uniform
      h[0] = fmaf(xk, wr[0], h[0]);
      h[1] = fmaf(xk, wr[1], h[1]);
      h[2] = fmaf(xk, wr[2], h[2]);
      h[3] = fmaf(xk, wr[3], h[3]);
    }
    __syncthreads();
  }

  // bias + ReLU; each (wave, j) written exactly once -> no reduction
#pragma unroll
  for (int i = 0; i < 4; ++i)
    hfull[l * 33 + 4 * w + i] = fmaxf(h[i] + b1[4 * w + i], 0.f);
  __syncthreads();

  // layer 2: wave w -> classes [8w, 8w+8)
  float pa[8];
#pragma unroll
  for (int c = 0; c < 8; ++c) pa[c] = b2[8 * w + c];
#pragma unroll 4
  for (int kk = 0; kk < 32; ++kk) {
    float hk = hfull[l * 33 + kk];
    const float* w2r = W2 + kk * N_CLASS + 8 * w;    // uniform
#pragma unroll
    for (int c = 0; c < 8; ++c) pa[c] = fmaf(hk, w2r[c], pa[c]);
  }
#pragma unroll
  for (int c = 0; c < 8; ++c) ps[l * 65 + 8 * w + c] = pa[c];
  __syncthreads();

  // softmax: 8 threads per node (same-wave shuffle groups)
  {
    int n = t >> 3, ck = (t & 7) * 8;
    float q[8];
    float m = -1e30f;
#pragma unroll
    for (int i = 0; i < 8; ++i) { q[i] = ps[n * 65 + ck + i]; m = fmaxf(m, q[i]); }
    m = fmaxf(m, __shfl_xor(m, 1));
    m = fmaxf(m, __shfl_xor(m, 2));
    m = fmaxf(m, __shfl_xor(m, 4));
    float s = 0.f;
#pragma unroll
    for (int i = 0; i < 8; ++i) { q[i] = expf(q[i] - m); s += q[i]; }
    s += __shfl_xor(s, 1);
    s += __shfl_xor(s, 2);
    s += __shfl_xor(s, 4);
    float inv = 1.f / s;
    if (n0 + n < N_NODES) {
      half8 o;
#pragma unroll
      for (int i = 0; i < 8; ++i) o[i] = (half_t)(q[i] * inv);
      *(half8*)(P + (size_t)(n0 + n) * N_CLASS + ck) = o;
    }
  }
}

// ---------------- SpMM + 0.5*tanh (+ fused final softmax) ----------------
// wave per dst node; 8 edge-subgroups x 8 channel-octets; 16B half8 gathers.

template <int FINAL>
__global__ __launch_bounds__(256) void spmm_kernel(const int2* __restrict__ rr,
                                                   const int2* __restrict__ ep,
                                                   const half_t* __restrict__ pin,
                                                   void* __restrict__ pout_) {
  int node = blockIdx.x * 4 + (threadIdx.x >> 6);
  int lane = threadIdx.x & 63;
  int g = lane >> 3;     // edge subgroup 0..7
  int s = lane & 7;      // channel octet: channels 8s..8s+7
  int2 be = rr[node];
  int beg = be.x, end = be.y;
  float acc[8];
#pragma unroll
  for (int i = 0; i < 8; ++i) acc[i] = 0.f;
  const long long* epl = (const long long*)ep;
  for (int base = beg; base < end; base += 64) {
    int idx = base + lane;
    long long raw = (idx < end) ? __builtin_nontemporal_load(epl + idx) : 0LL;
    int ex = (int)raw;
    float ev = __int_as_float((int)(raw >> 32));
    int cnt = min(64, end - base);
#pragma unroll 4
    for (int j = g; j < cnt; j += 8) {
      int   sj = __shfl(ex, j);
      float vj = __shfl(ev, j);
      half8 hv = *(const half8*)(pin + ((size_t)sj << 6) + (s << 3));
#pragma unroll
      for (int i = 0; i < 8; ++i) acc[i] = fmaf(vj, (float)hv[i], acc[i]);
    }
  }
#pragma unroll
  for (int off = 8; off <= 32; off <<= 1)
#pragma unroll
    for (int i = 0; i < 8; ++i) acc[i] += __shfl_xor(acc[i], off);
  float r[8];
#pragma unroll
  for (int i = 0; i < 8; ++i) r[i] = 0.5f * tanhf(acc[i]);
  if (FINAL) {
    float m = r[0];
#pragma unroll
    for (int i = 1; i < 8; ++i) m = fmaxf(m, r[i]);
    m = fmaxf(m, __shfl_xor(m, 1));
    m = fmaxf(m, __shfl_xor(m, 2));
    m = fmaxf(m, __shfl_xor(m, 4));
    float e[8], sum = 0.f;
#pragma unroll
    for (int i = 0; i < 8; ++i) { e[i] = expf(r[i] - m); sum += e[i]; }
    sum += __shfl_xor(sum, 1);
    sum += __shfl_xor(sum, 2);
    sum += __shfl_xor(sum, 4);
    float inv = 1.f / sum;
    if (g == 0) {
      float* op = (float*)pout_ + ((size_t)node << 6) + (s << 3);
      *(float4*)op = make_float4(e[0] * inv, e[1] * inv, e[2] * inv, e[3] * inv);
      *(float4*)(op + 4) = make_float4(e[4] * inv, e[5] * inv, e[6] * inv, e[7] * inv);
    }
  } else {
    if (g == 0) {
      half8 o;
#pragma unroll
      for (int i = 0; i < 8; ++i) o[i] = (half_t)r[i];
      *(half8*)((half_t*)pout_ + ((size_t)node << 6) + (s << 3)) = o;
    }
  }
}

// ---------------- launch ----------------

extern "C" void kernel_launch(void* const* d_in, const int* in_sizes, int n_in,
                              void* d_out, int out_size, void* d_ws, size_t ws_size,
                              hipStream_t stream) {
  const float* x    = (const float*)d_in[0];
  const int*   esrc = (const int*)d_in[1];
  const int*   edst = (const int*)d_in[2];
  const float* evl  = (const float*)d_in[3];
  const float* W1   = (const float*)d_in[4];
  const float* b1   = (const float*)d_in[5];
  const float* W2   = (const float*)d_in[6];
  const float* b2   = (const float*)d_in[7];

  char* ws = (char*)d_ws;
  int2*   st   = (int2*)  (ws);               // 16.0 MB (dead after build_csr)
  half_t* Pa   = (half_t*)(ws);               // 6.4 MB (aliases st)
  half_t* Pb   = (half_t*)(ws + 6400000);     // 6.4 MB (aliases st)
  int2*   ep   = (int2*)  (ws + 16015360);    // 16.0 MB
  int*    bcur = (int*)   (ws + 32030720);    // 391 ints
  int2*   rr   = (int2*)  (ws + 32032384);    // 50000 int2

  hipMemsetAsync(bcur, 0, NBUCK * sizeof(int), stream);

  bin_edges<<<224, 256, 0, stream>>>(esrc, edst, evl, bcur, st);
  build_csr<<<NBUCK, 256, 0, stream>>>(bcur, st, rr, ep);

  mlp_kernel<<<782, 512, 0, stream>>>(x, W1, b1, W2, b2, Pa);

  spmm_kernel<0><<<12500, 256, 0, stream>>>(rr, ep, Pa, Pb);
  spmm_kernel<0><<<12500, 256, 0, stream>>>(rr, ep, Pb, Pa);
  spmm_kernel<0><<<12500, 256, 0, stream>>>(rr, ep, Pa, Pb);
  spmm_kernel<1><<<12500, 256, 0, stream>>>(rr, ep, Pb, d_out);
}